// Round 9
// baseline (389.851 us; speedup 1.0000x reference)
//
#include <hip/hip_runtime.h>
#include <hip/hip_bf16.h>

#define NEG_SLOPE 0.2f
typedef unsigned int uint32;

#define BSHIFT 9
#define BSIZE 512          // nodes per bucket
#define MAXB 256           // max buckets (N < 131072)
#define PCHUNK 2048        // edges per partition block
#define PEPT 8             // PCHUNK / 256
#define BSTRIDE 12288      // fixed slot per bucket (avg 8673, +38 sigma slack)
#define PNODES 256         // nodes per pool_stream block
#define PSPAN 16           // max graphs spanned per pool block (fallback past)

typedef __attribute__((ext_vector_type(8))) __bf16 bf16x8;
typedef __attribute__((ext_vector_type(4))) float f32x4;
typedef __attribute__((ext_vector_type(2))) float f32x2;

__device__ __forceinline__ float selu_f(float x) {
    const float a = 1.6732632423543772f, s = 1.0507009873554805f;
    return x > 0.0f ? s * x : s * a * (__expf(x) - 1.0f);
}

__device__ __forceinline__ unsigned short f2bf(float x) {
    uint32 u = __float_as_uint(x);
    uint32 r = (u + 0x7fff + ((u >> 16) & 1)) >> 16;   // RNE
    return (unsigned short)r;
}
__device__ __forceinline__ float bf_lo(uint32 g) { return __uint_as_float(g << 16); }
__device__ __forceinline__ float bf_hi(uint32 g) { return __uint_as_float(g & 0xffff0000u); }

// OCP e4m3 HW converts (gfx950): 2 features per instruction
__device__ __forceinline__ f32x2 f8x2lo(uint32 w) { return __builtin_amdgcn_cvt_pk_f32_fp8((int)w, false); }
__device__ __forceinline__ f32x2 f8x2hi(uint32 w) { return __builtin_amdgcn_cvt_pk_f32_fp8((int)w, true); }

// ---- prep9: repack W1/W2 (blocks 0,1) + graph_bounds + ws zeroing --------
__global__ __launch_bounds__(256) void prep9(const float* __restrict__ W1,
                                             const float* __restrict__ W2,
                                             unsigned short* __restrict__ Wb,
                                             const int* __restrict__ batch,
                                             int* __restrict__ gstart,
                                             int* __restrict__ gcur0,
                                             float* __restrict__ gsum,
                                             int N, int G) {
    int b = blockIdx.x, t = threadIdx.x;
    if (b < 2) {
        if (b == 0 && t < MAXB) gcur0[t] = 0;
        // repack W[128][128] fp32 -> B-fragment-ordered bf16 hi/lo
        const float* W = b ? W2 : W1;
        unsigned short* oh = Wb + (size_t)b * 32768;
        unsigned short* ol = oh + 16384;
        for (int d = t; d < 16384; d += 256) {
            int j = d & 7, nn = (d >> 3) & 127, g = d >> 10;
            float v = W[(g * 8 + j) * 128 + nn];
            uint32 hu = f2bf(v);
            float hv = __uint_as_float(hu << 16);
            oh[d] = (unsigned short)hu;
            ol[d] = f2bf(v - hv);
        }
    } else {
        int i = (b - 2) * 256 + t;
        if (i < G * 128) gsum[i] = 0.0f;
        // graph bounds from sorted batch
        if (i < N) {
            int bb = batch[i];
            int bp = (i == 0) ? -1 : batch[i - 1];
            for (int q = bp + 1; q <= bb; ++q) gstart[q] = i;
            if (i == N - 1)
                for (int q = bb + 1; q <= G; ++q) gstart[q] = N;
        }
    }
}

// ------------- partition edges into strided bucket slots ------------------
__global__ __launch_bounds__(256) void partition_edges(const int* __restrict__ ei,
                                                       int* __restrict__ gcur0,
                                                       uint32* __restrict__ tmp,
                                                       int E, int TOT) {
    __shared__ int lcnt[MAXB];
    __shared__ int lstart[MAXB];
    __shared__ int lcur[MAXB];
    __shared__ int gbase[MAXB];
    __shared__ int wsums[4];
    __shared__ uint32 staged[PCHUNK];
    __shared__ unsigned char bslot[PCHUNK];
    int t = threadIdx.x;
    int lane = t & 63, w = t >> 6;
    int eb = blockIdx.x * PCHUNK;
    int sreg[PEPT], dreg[PEPT];
    #pragma unroll
    for (int k = 0; k < PEPT; ++k) {
        int e = eb + k * 256 + t;
        if (e < TOT) {
            if (e < E) { sreg[k] = ei[e]; dreg[k] = ei[E + e]; }
            else       { sreg[k] = dreg[k] = e - E; }
        } else dreg[k] = -1;
    }
    lcnt[t] = 0;
    __syncthreads();
    #pragma unroll
    for (int k = 0; k < PEPT; ++k)
        if (dreg[k] >= 0) atomicAdd(&lcnt[dreg[k] >> BSHIFT], 1);
    __syncthreads();
    int v = lcnt[t];
    int incl = v;
    #pragma unroll
    for (int off = 1; off < 64; off <<= 1) {
        int u = __shfl_up(incl, off);
        if (lane >= off) incl += u;
    }
    if (lane == 63) wsums[w] = incl;
    __syncthreads();
    int wadd = 0;
    #pragma unroll
    for (int k = 0; k < 4; ++k) wadd += (k < w) ? wsums[k] : 0;
    int ex = incl + wadd - v;
    lstart[t] = ex;
    lcur[t] = ex;
    if (v > 0) gbase[t] = t * BSTRIDE + atomicAdd(&gcur0[t], v);
    __syncthreads();
    #pragma unroll
    for (int k = 0; k < PEPT; ++k) {
        int d = dreg[k];
        if (d >= 0) {
            int b = d >> BSHIFT;
            int p = atomicAdd(&lcur[b], 1);
            staged[p] = ((uint32)(d & (BSIZE - 1)) << 17) | (uint32)sreg[k];
            bslot[p] = (unsigned char)b;
        }
    }
    __syncthreads();
    int nvalid = TOT - eb; if (nvalid > PCHUNK) nvalid = PCHUNK;
    for (int i = t; i < nvalid; i += 256) {
        int b = bslot[i];
        tmp[gbase[b] + (i - lstart[b])] = staged[i];
    }
}

// ------------- per-bucket: per-node scan -> rowptr/rowend + col -----------
__global__ __launch_bounds__(1024) void bucket_build(const uint32* __restrict__ tmp,
                                                     const int* __restrict__ gcur0,
                                                     int* __restrict__ rowptr,
                                                     int* __restrict__ rowend,
                                                     int* __restrict__ col,
                                                     int N, int NB) {
    __shared__ int cnt[BSIZE];
    __shared__ int bsums[4];
    int b = blockIdx.x, t = threadIdx.x;
    int lo = b << BSHIFT;
    int nn = N - lo; if (nn > BSIZE) nn = BSIZE;
    if (t < BSIZE) cnt[t] = 0;
    __syncthreads();
    int ebeg = b * BSTRIDE;
    int eend = ebeg + gcur0[b];
    for (int i = ebeg + t; i < eend; i += 1024)
        atomicAdd(&cnt[tmp[i] >> 17], 1);
    __syncthreads();
    int c0 = 0, c1 = 0, s2 = 0;
    if (t < 256) {
        c0 = cnt[2 * t]; c1 = cnt[2 * t + 1];
        s2 = c0 + c1;
    }
    // wave shfl scan over the 256 participating threads (4 waves)
    int lane = t & 63, w = t >> 6;
    int incl = s2;
    #pragma unroll
    for (int off = 1; off < 64; off <<= 1) {
        int u = __shfl_up(incl, off);
        if (lane >= off) incl += u;
    }
    if (t < 256 && lane == 63) bsums[w] = incl;
    __syncthreads();
    if (t < 256) {
        int wadd = 0;
        #pragma unroll
        for (int k = 0; k < 4; ++k) wadd += (k < w) ? bsums[k] : 0;
        int ex = incl + wadd - s2;
        int st0 = ebeg + ex, st1 = st0 + c0;
        if (2 * t < nn)     { rowptr[lo + 2 * t] = st0;     rowend[lo + 2 * t] = st0 + c0; }
        if (2 * t + 1 < nn) { rowptr[lo + 2 * t + 1] = st1; rowend[lo + 2 * t + 1] = st1 + c1; }
        cnt[2 * t] = st0; cnt[2 * t + 1] = st1;
    }
    __syncthreads();
    for (int i = ebeg + t; i < eend; i += 1024) {
        uint32 u = tmp[i];
        int p = atomicAdd(&cnt[u >> 17], 1);
        col[p] = (int)(u & 0x1FFFFu);
    }
}

// ---- shared MFMA core: A(bf16) x (B_hi + B_lo), 32 rows/wave -------------
// FP8: pack hb rows as OCP e4m3 (128 B/row) for the gather.
template<bool FP8>
__device__ __forceinline__ void gemm_core(const bf16x8 ah[2][4],
                                          const __bf16* Wl,
                                          const float* a_src, const float* a_dst,
                                          uint32* hb, float* as_, float* ad_,
                                          int rbase, int n, int col16, int quad) {
    f32x4 acc[2][8];
    #pragma unroll
    for (int mt = 0; mt < 2; ++mt)
        #pragma unroll
        for (int t = 0; t < 8; ++t) acc[mt][t] = (f32x4)(0.0f);

    #pragma unroll
    for (int c = 0; c < 4; ++c) {
        #pragma unroll
        for (int t = 0; t < 8; ++t) {
            int off = (((c * 4 + quad) * 128) + t * 16 + col16) * 8;
            bf16x8 bh = *(const bf16x8*)&Wl[off];
            bf16x8 bl = *(const bf16x8*)&Wl[16384 + off];
            #pragma unroll
            for (int mt = 0; mt < 2; ++mt) {
                acc[mt][t] = __builtin_amdgcn_mfma_f32_16x16x32_bf16(ah[mt][c], bh, acc[mt][t], 0, 0, 0);
                acc[mt][t] = __builtin_amdgcn_mfma_f32_16x16x32_bf16(ah[mt][c], bl, acc[mt][t], 0, 0, 0);
            }
        }
    }
    float asv[8], adv[8];
    #pragma unroll
    for (int t = 0; t < 8; ++t) { asv[t] = a_src[t * 16 + col16]; adv[t] = a_dst[t * 16 + col16]; }
    #pragma unroll
    for (int mt = 0; mt < 2; ++mt) {
        #pragma unroll
        for (int reg = 0; reg < 4; ++reg) {
            float s = 0.0f, d = 0.0f;
            #pragma unroll
            for (int t = 0; t < 8; ++t) {
                float v = acc[mt][t][reg];
                s += v * asv[t]; d += v * adv[t];
            }
            #pragma unroll
            for (int off = 1; off < 16; off <<= 1) {
                s += __shfl_xor(s, off);
                d += __shfl_xor(d, off);
            }
            int r = rbase + mt * 16 + quad * 4 + reg;
            if (col16 == 0 && r < n) { as_[r] = s; ad_[r] = d; }
        }
    }
    #pragma unroll
    for (int mt = 0; mt < 2; ++mt)
    #pragma unroll
    for (int t = 0; t < 8; ++t)
    #pragma unroll
    for (int reg = 0; reg < 4; ++reg) {
        float v = acc[mt][t][reg];
        int r = rbase + mt * 16 + quad * 4 + reg;
        if (FP8) {
            float p1 = __shfl_xor(v, 1);
            uint32 pk = (uint32)__builtin_amdgcn_cvt_pk_fp8_f32(v, p1, 0, false);
            uint32 pk2 = __shfl_xor(pk, 2);
            if (!(col16 & 3) && r < n)
                hb[(size_t)r * 32 + t * 4 + (col16 >> 2)] = (pk & 0xffffu) | (pk2 << 16);
        } else {
            float p = __shfl_xor(v, 1);
            if (!(col16 & 1) && r < n) {
                uint32 pkb = (uint32)f2bf(v) | ((uint32)f2bf(p) << 16);
                hb[(size_t)r * 64 + t * 8 + (col16 >> 1)] = pkb;
            }
        }
    }
}

// 512-thread blocks: 256 rows/block, same 64KB LDS -> 16 waves/CU
// both gemms emit FP8 hb rows (128 B/row gather buffer)
__global__ __launch_bounds__(512) void gemm_mfma_f32(const float* __restrict__ X,
                                                     const unsigned short* __restrict__ Wbh,
                                                     const float* __restrict__ a_src,
                                                     const float* __restrict__ a_dst,
                                                     uint32* __restrict__ hb,
                                                     float* __restrict__ as_,
                                                     float* __restrict__ ad_, int n) {
    __shared__ __bf16 Wl[32768];   // 64 KB hi+lo
    const int tid = threadIdx.x;
    {
        const uint4* sw = (const uint4*)Wbh;
        uint4* dw = (uint4*)Wl;
        for (int i = tid; i < 4096; i += 512) dw[i] = sw[i];
    }
    const int lane = tid & 63, wid = tid >> 6;
    const int col16 = lane & 15, quad = lane >> 4;
    const int rbase = blockIdx.x * 256 + wid * 32;
    bf16x8 ah[2][4];
    #pragma unroll
    for (int mt = 0; mt < 2; ++mt) {
        int r = rbase + mt * 16 + col16;
        bool ok = (r < n);
        const float* xp = X + (size_t)r * 128;
        #pragma unroll
        for (int c = 0; c < 4; ++c) {
            int k0 = c * 32 + quad * 8;
            float4 x0 = ok ? *(const float4*)(xp + k0)     : make_float4(0.f,0.f,0.f,0.f);
            float4 x1 = ok ? *(const float4*)(xp + k0 + 4) : make_float4(0.f,0.f,0.f,0.f);
            float xs[8] = {x0.x,x0.y,x0.z,x0.w,x1.x,x1.y,x1.z,x1.w};
            #pragma unroll
            for (int j = 0; j < 8; ++j) ah[mt][c][j] = (__bf16)xs[j];
        }
    }
    __syncthreads();
    gemm_core<true>(ah, Wl, a_src, a_dst, hb, as_, ad_, rbase, n, col16, quad);
}

__global__ __launch_bounds__(512) void gemm_mfma_bf16(const __bf16* __restrict__ X,
                                                      const unsigned short* __restrict__ Wbh,
                                                      const float* __restrict__ a_src,
                                                      const float* __restrict__ a_dst,
                                                      uint32* __restrict__ hb,
                                                      float* __restrict__ as_,
                                                      float* __restrict__ ad_, int n) {
    __shared__ __bf16 Wl[32768];
    const int tid = threadIdx.x;
    {
        const uint4* sw = (const uint4*)Wbh;
        uint4* dw = (uint4*)Wl;
        for (int i = tid; i < 4096; i += 512) dw[i] = sw[i];
    }
    const int lane = tid & 63, wid = tid >> 6;
    const int col16 = lane & 15, quad = lane >> 4;
    const int rbase = blockIdx.x * 256 + wid * 32;
    bf16x8 ah[2][4];
    const bf16x8 zz = (bf16x8)((__bf16)0.0f);
    #pragma unroll
    for (int mt = 0; mt < 2; ++mt) {
        int r = rbase + mt * 16 + col16;
        bool ok = (r < n);
        const __bf16* xp = X + (size_t)r * 128;
        #pragma unroll
        for (int c = 0; c < 4; ++c)
            ah[mt][c] = ok ? *(const bf16x8*)(xp + c * 32 + quad * 8) : zz;
    }
    __syncthreads();
    gemm_core<true>(ah, Wl, a_src, a_dst, hb, as_, ad_, rbase, n, col16, quad);
}

// --------- fused GAT fp8 v2: paired-row uint4 gather ----------------------
// Proven alpha phase + loop (4 nodes/wave, 16-lane groups, 8-edge batches,
// A/B lookahead). Gather change: lanes 0-7 of a group load edge 2k, lanes
// 8-15 load edge 2k+1, each lane a full uint4 (16 fp8 feats, words 4*l7..).
// 4 load instrs per 8-edge batch (was 8). shfl_xor(.,8) merges halves.
#define GIDX4(SARR, T0) { _Pragma("unroll") \
    for (int k_ = 0; k_ < 4; ++k_) { int t_ = (T0) + 2 * k_ + sub; \
        int sv_ = (t_ < 16) ? s0 : s1; \
        int si_ = __shfl(sv_, base + (t_ & 15)); \
        SARR[k_] = (t_ < cnt) ? si_ : 0; } }

#define GW4(WARR, T0) { _Pragma("unroll") \
    for (int k_ = 0; k_ < 4; ++k_) { int t_ = (T0) + 2 * k_ + sub; \
        float wv_ = (t_ < 16) ? w0 : w1; \
        float wf_ = __shfl(wv_, base + (t_ & 15)); \
        WARR[k_] = (t_ < cnt) ? wf_ : 0.0f; } }

#define GLOAD4_F8(GARR, SARR) { _Pragma("unroll") \
    for (int k_ = 0; k_ < 4; ++k_) GARR[k_] = hb4[(uint32)SARR[k_] * 8u + l7]; }

#define GCONSUME4_F8(GARR, WARR) { _Pragma("unroll") \
    for (int k_ = 0; k_ < 4; ++k_) { \
        f32x2 wv_ = (f32x2)WARR[k_]; \
        ac[0] = __builtin_elementwise_fma(wv_, f8x2lo(GARR[k_].x), ac[0]); \
        ac[1] = __builtin_elementwise_fma(wv_, f8x2hi(GARR[k_].x), ac[1]); \
        ac[2] = __builtin_elementwise_fma(wv_, f8x2lo(GARR[k_].y), ac[2]); \
        ac[3] = __builtin_elementwise_fma(wv_, f8x2hi(GARR[k_].y), ac[3]); \
        ac[4] = __builtin_elementwise_fma(wv_, f8x2lo(GARR[k_].z), ac[4]); \
        ac[5] = __builtin_elementwise_fma(wv_, f8x2hi(GARR[k_].z), ac[5]); \
        ac[6] = __builtin_elementwise_fma(wv_, f8x2lo(GARR[k_].w), ac[6]); \
        ac[7] = __builtin_elementwise_fma(wv_, f8x2hi(GARR[k_].w), ac[7]); } }

__global__ __launch_bounds__(256) void gat_csr6_f8(const int* __restrict__ rowptr,
                                                   const int* __restrict__ rowend,
                                                   const int* __restrict__ col,
                                                   const uint4* __restrict__ hb4,
                                                   const float* __restrict__ as_,
                                                   const float* __restrict__ ad_,
                                                   const float* __restrict__ bias,
                                                   uint4* __restrict__ outb, int n) {
    const int wid = threadIdx.x >> 6;
    const int lane = threadIdx.x & 63;
    const int q = lane >> 4, l = lane & 15;          // node sub-group, lane in group
    const int base = lane & 48;                      // q * 16
    const int sub = (lane >> 3) & 1;                 // edge-pair half
    const int l7 = lane & 7;                         // word-quad within row
    const int node = blockIdx.x * 16 + wid * 4 + q;
    const bool valid = node < n;
    int beg = 0, end = 0;
    if (valid) { beg = rowptr[node]; end = rowend[node]; }
    float add = valid ? ad_[node] : 0.0f;
    int deg = end - beg;
    int m1 = max(deg, __shfl_xor(deg, 16));
    int mdeg = max(m1, __shfl_xor(m1, 32));
    float s = 0.0f;
    f32x2 ac[8];
    #pragma unroll
    for (int p = 0; p < 8; ++p) ac[p] = (f32x2)(0.0f);

    for (int cb = 0; cb < mdeg; cb += 32) {
        int j0 = beg + cb + l, j1 = j0 + 16;
        bool e0 = (j0 < end), e1 = (j1 < end);
        int s0 = e0 ? col[j0] : 0;
        int s1 = e1 ? col[j1] : 0;
        int cnt = end - beg - cb;
        cnt = (cnt < 0) ? 0 : (cnt > 32 ? 32 : cnt);
        int rem = mdeg - cb; if (rem > 32) rem = 32;
        const int NB8 = (rem + 7) >> 3;              // 1..4, wave-uniform

        int si[4]; uint4 gA[4], gB[4]; float wA[4], wB[4];

        // batch 0 loads go out first -- alpha phase hides under them
        GIDX4(si, 0); GLOAD4_F8(gA, si);

        float v0 = as_[s0] + add;
        float v1 = as_[s1] + add;
        v0 = (v0 > 0.0f) ? v0 : NEG_SLOPE * v0;
        v1 = (v1 > 0.0f) ? v1 : NEG_SLOPE * v1;
        float w0 = e0 ? __expf(v0) : 0.0f;
        float w1 = e1 ? __expf(v1) : 0.0f;
        float ws = w0 + w1;
        #pragma unroll
        for (int off = 8; off > 0; off >>= 1) ws += __shfl_xor(ws, off);
        s += ws;
        GW4(wA, 0);

        int b = 0;
        while (true) {
            bool moreB = (b + 1 < NB8);
            if (moreB) { GIDX4(si, (b + 1) * 8); GLOAD4_F8(gB, si); GW4(wB, (b + 1) * 8); }
            GCONSUME4_F8(gA, wA);
            if (!moreB) break;
            bool moreA = (b + 2 < NB8);
            if (moreA) { GIDX4(si, (b + 2) * 8); GLOAD4_F8(gA, si); GW4(wA, (b + 2) * 8); }
            GCONSUME4_F8(gB, wB);
            if (!moreA) break;
            b += 2;
        }
    }
    // merge the two edge-halves: lanes l and l^8 hold partials of the same
    // feature slice (l7*16 .. +16) of the same node
    float e[16];
    #pragma unroll
    for (int i = 0; i < 8; ++i) {
        e[2 * i]     = ac[i].x + __shfl_xor(ac[i].x, 8);
        e[2 * i + 1] = ac[i].y + __shfl_xor(ac[i].y, 8);
    }
    if (valid && sub == 0) {
        float inv = 1.0f / s;
        const float* bp = &bias[l7 * 16];
        uint32 ow[8];
        #pragma unroll
        for (int i = 0; i < 8; ++i) {
            float r0 = selu_f(e[2 * i] * inv + bp[2 * i]);
            float r1 = selu_f(e[2 * i + 1] * inv + bp[2 * i + 1]);
            ow[i] = (uint32)f2bf(r0) | ((uint32)f2bf(r1) << 16);
        }
        uint4* orow = outb + (uint32)node * 16u + l7 * 2;
        orow[0] = make_uint4(ow[0], ow[1], ow[2], ow[3]);
        orow[1] = make_uint4(ow[4], ow[5], ow[6], ow[7]);
    }
}

// ------- streaming mean-pool: coalesced read of h2b, reg-accum by graph ---
__global__ __launch_bounds__(256) void pool_stream(const uint32* __restrict__ act,
                                                   const int* __restrict__ batch,
                                                   float* __restrict__ gsum, int N) {
    __shared__ float pacc[PSPAN][128];
    const int t = threadIdx.x, wid = t >> 6, u = t & 63;
    const int n0 = blockIdx.x * PNODES;
    int n1 = n0 + PNODES; if (n1 > N) n1 = N;
    for (int i = t; i < PSPAN * 128; i += 256) pacc[i >> 7][i & 127] = 0.f;
    __syncthreads();
    const int gfirst = batch[n0];
    float a0 = 0.f, a1 = 0.f;
    int gcur = gfirst;
    for (int nd = n0 + wid; nd < n1; nd += 4) {
        int g = batch[nd];
        if (g != gcur) {
            int slot = gcur - gfirst;
            if (slot < PSPAN) {
                atomicAdd(&pacc[slot][2 * u], a0);
                atomicAdd(&pacc[slot][2 * u + 1], a1);
            } else {
                atomicAdd(&gsum[(size_t)gcur * 128 + 2 * u], a0);
                atomicAdd(&gsum[(size_t)gcur * 128 + 2 * u + 1], a1);
            }
            a0 = a1 = 0.f; gcur = g;
        }
        uint32 gv = act[(size_t)nd * 64 + u];
        a0 += bf_lo(gv); a1 += bf_hi(gv);
    }
    {
        int slot = gcur - gfirst;
        if (slot < PSPAN) {
            atomicAdd(&pacc[slot][2 * u], a0);
            atomicAdd(&pacc[slot][2 * u + 1], a1);
        } else {
            atomicAdd(&gsum[(size_t)gcur * 128 + 2 * u], a0);
            atomicAdd(&gsum[(size_t)gcur * 128 + 2 * u + 1], a1);
        }
    }
    __syncthreads();
    int lastg = batch[n1 - 1];
    int nslots = lastg - gfirst + 1; if (nslots > PSPAN) nslots = PSPAN;
    for (int i = t; i < nslots * 128; i += 256) {
        float v = pacc[i >> 7][i & 127];
        if (v != 0.f)
            atomicAdd(&gsum[(size_t)(gfirst + (i >> 7)) * 128 + (i & 127)], v);
    }
}

// ------------- head: mean from gsum (fp32) + MLP + log-softmax ------------
__global__ __launch_bounds__(128) void pool_head2(const float* __restrict__ gsum,
                                                  const int* __restrict__ gstart,
                                                  const float* __restrict__ Wfc1,
                                                  const float* __restrict__ bfc1,
                                                  const float* __restrict__ Wfc2,
                                                  const float* __restrict__ bfc2,
                                                  float* __restrict__ out) {
    __shared__ float p[128];
    __shared__ float q[64];
    __shared__ float l[10];
    __shared__ float red[2];
    int g = blockIdx.x, t = threadIdx.x;
    int lo = gstart[g], hi = gstart[g + 1];
    float c = fmaxf((float)(hi - lo), 1.0f);
    p[t] = selu_f(gsum[(size_t)g * 128 + t] / c);
    __syncthreads();
    if (t < 64) {
        float a = bfc1[t];
        #pragma unroll 8
        for (int k = 0; k < 128; ++k) a += p[k] * Wfc1[k * 64 + t];
        q[t] = selu_f(a);
    }
    __syncthreads();
    if (t < 10) {
        float a = bfc2[t];
        #pragma unroll
        for (int k = 0; k < 64; ++k) a += q[k] * Wfc2[k * 10 + t];
        l[t] = a;
    }
    __syncthreads();
    if (t == 0) {
        float mx = l[0];
        for (int c2 = 1; c2 < 10; ++c2) mx = fmaxf(mx, l[c2]);
        float sum = 0.0f;
        for (int c2 = 0; c2 < 10; ++c2) sum += __expf(l[c2] - mx);
        red[0] = mx; red[1] = logf(sum);
    }
    __syncthreads();
    if (t < 10) out[g * 10 + t] = l[t] - red[0] - red[1];
}

extern "C" void kernel_launch(void* const* d_in, const int* in_sizes, int n_in,
                              void* d_out, int out_size, void* d_ws, size_t ws_size,
                              hipStream_t stream) {
    const float* x      = (const float*)d_in[0];
    const int*   ei     = (const int*)d_in[1];
    const int*   batch  = (const int*)d_in[2];
    const float* W1     = (const float*)d_in[3];
    const float* asrc1  = (const float*)d_in[4];
    const float* adst1  = (const float*)d_in[5];
    const float* b1     = (const float*)d_in[6];
    const float* W2     = (const float*)d_in[7];
    const float* asrc2  = (const float*)d_in[8];
    const float* adst2  = (const float*)d_in[9];
    const float* b2     = (const float*)d_in[10];
    const float* Wfc1   = (const float*)d_in[11];
    const float* bfc1   = (const float*)d_in[12];
    const float* Wfc2   = (const float*)d_in[13];
    const float* bfc2   = (const float*)d_in[14];
    float* out = (float*)d_out;

    const int N = in_sizes[0] / 128;
    const int E = in_sizes[1] / 2;
    const int G = out_size / 10;
    const int TOT = E + N;
    const int NB = ((N - 1) >> BSHIFT) + 1;
    const int GB = (N + 255) / 256;
    const int PH = (TOT + PCHUNK - 1) / PCHUNK;
    const int GemmG = (N + 255) / 256;

    // workspace layout
    uint32* hb    = (uint32*)d_ws;                   // N*64  (h rows: fp8, 128B used)
    uint32* h2b   = hb + (size_t)N * 64;             // N*64  (bf16 layer outputs)
    uint32* tmp   = h2b + (size_t)N * 64;            // NB*BSTRIDE (strided buckets)
    int*    col   = (int*)(tmp + (size_t)NB * BSTRIDE); // NB*BSTRIDE (strided)
    float* as_    = (float*)(col + (size_t)NB * BSTRIDE); // N
    float* ad_    = as_ + N;                         // N
    int*   gstart = (int*)(ad_ + N);                 // G+1
    int*   rowptr = gstart + (G + 2);                // N
    int*   rowend = rowptr + (N + 2);                // N
    int*   gcur0  = rowend + (N + 2);                // MAXB (zeroed in prep9)
    unsigned short* Wb = (unsigned short*)(((uintptr_t)(gcur0 + MAXB) + 255) & ~(uintptr_t)255);
    // Wb: 2 layers x (16384 hi + 16384 lo) ushorts = 128 KB
    float* gsum = (float*)(Wb + 2 * 32768);          // G*128 fp32 pooled sums

    const int gatGrid = (N + 15) / 16;

    // ---------------- prep (repack + gbounds + zeroing) + CSR build -------
    prep9<<<2 + GB, 256, 0, stream>>>(W1, W2, Wb, batch, gstart, gcur0, gsum, N, G);
    partition_edges<<<PH, 256, 0, stream>>>(ei, gcur0, tmp, E, TOT);
    bucket_build<<<NB, 1024, 0, stream>>>(tmp, gcur0, rowptr, rowend, col, N, NB);

    // ---------------- layer 1 (fp8 gather; attention logits stay fp32) ----
    gemm_mfma_f32<<<GemmG, 512, 0, stream>>>(x, Wb, asrc1, adst1, hb, as_, ad_, N);
    gat_csr6_f8<<<gatGrid, 256, 0, stream>>>(rowptr, rowend, col, (const uint4*)hb,
                                             as_, ad_, b1, (uint4*)h2b, N);

    // ---------------- layer 2 (fp8 gather) ----------------
    gemm_mfma_bf16<<<GemmG, 512, 0, stream>>>((const __bf16*)h2b, Wb + 32768, asrc2, adst2, hb, as_, ad_, N);
    gat_csr6_f8<<<gatGrid, 256, 0, stream>>>(rowptr, rowend, col, (const uint4*)hb,
                                             as_, ad_, b2, (uint4*)h2b, N);

    // ---------------- pool (streaming) + head ----------------
    pool_stream<<<(N + PNODES - 1) / PNODES, 256, 0, stream>>>(h2b, batch, gsum, N);
    pool_head2<<<G, 128, 0, stream>>>(gsum, gstart, Wfc1, bfc1, Wfc2, bfc2, out);
}

// Round 10
// 350.096 us; speedup vs baseline: 1.1136x; 1.1136x over previous
//
#include <hip/hip_runtime.h>
#include <hip/hip_bf16.h>

#define NEG_SLOPE 0.2f
typedef unsigned int uint32;

#define BSHIFT 9
#define BSIZE 512          // nodes per bucket
#define MAXB 256           // max buckets (N < 131072)
#define PCHUNK 2048        // edges per partition block
#define PEPT 8             // PCHUNK / 256
#define BSTRIDE 12288      // fixed slot per bucket (avg 8673, +38 sigma slack)
#define PNODES 256         // nodes per pool_stream block
#define PSPAN 16           // max graphs spanned per pool block (fallback past)

typedef __attribute__((ext_vector_type(8))) __bf16 bf16x8;
typedef __attribute__((ext_vector_type(4))) float f32x4;
typedef __attribute__((ext_vector_type(2))) float f32x2;

__device__ __forceinline__ float selu_f(float x) {
    const float a = 1.6732632423543772f, s = 1.0507009873554805f;
    return x > 0.0f ? s * x : s * a * (__expf(x) - 1.0f);
}

__device__ __forceinline__ unsigned short f2bf(float x) {
    uint32 u = __float_as_uint(x);
    uint32 r = (u + 0x7fff + ((u >> 16) & 1)) >> 16;   // RNE
    return (unsigned short)r;
}
__device__ __forceinline__ float bf_lo(uint32 g) { return __uint_as_float(g << 16); }
__device__ __forceinline__ float bf_hi(uint32 g) { return __uint_as_float(g & 0xffff0000u); }

// OCP e4m3 HW converts (gfx950): 2 features per instruction
__device__ __forceinline__ f32x2 f8x2lo(uint32 w) { return __builtin_amdgcn_cvt_pk_f32_fp8((int)w, false); }
__device__ __forceinline__ f32x2 f8x2hi(uint32 w) { return __builtin_amdgcn_cvt_pk_f32_fp8((int)w, true); }

// ---- prep9: repack W1/W2 (blocks 0,1) + graph_bounds + ws zeroing --------
__global__ __launch_bounds__(256) void prep9(const float* __restrict__ W1,
                                             const float* __restrict__ W2,
                                             unsigned short* __restrict__ Wb,
                                             const int* __restrict__ batch,
                                             int* __restrict__ gstart,
                                             int* __restrict__ gcur0,
                                             float* __restrict__ gsum,
                                             int N, int G) {
    int b = blockIdx.x, t = threadIdx.x;
    if (b < 2) {
        if (b == 0 && t < MAXB) gcur0[t] = 0;
        // repack W[128][128] fp32 -> B-fragment-ordered bf16 hi/lo
        const float* W = b ? W2 : W1;
        unsigned short* oh = Wb + (size_t)b * 32768;
        unsigned short* ol = oh + 16384;
        for (int d = t; d < 16384; d += 256) {
            int j = d & 7, nn = (d >> 3) & 127, g = d >> 10;
            float v = W[(g * 8 + j) * 128 + nn];
            uint32 hu = f2bf(v);
            float hv = __uint_as_float(hu << 16);
            oh[d] = (unsigned short)hu;
            ol[d] = f2bf(v - hv);
        }
    } else {
        int i = (b - 2) * 256 + t;
        if (i < G * 128) gsum[i] = 0.0f;
        // graph bounds from sorted batch
        if (i < N) {
            int bb = batch[i];
            int bp = (i == 0) ? -1 : batch[i - 1];
            for (int q = bp + 1; q <= bb; ++q) gstart[q] = i;
            if (i == N - 1)
                for (int q = bb + 1; q <= G; ++q) gstart[q] = N;
        }
    }
}

// ------------- partition edges into strided bucket slots ------------------
__global__ __launch_bounds__(256) void partition_edges(const int* __restrict__ ei,
                                                       int* __restrict__ gcur0,
                                                       uint32* __restrict__ tmp,
                                                       int E, int TOT) {
    __shared__ int lcnt[MAXB];
    __shared__ int lstart[MAXB];
    __shared__ int lcur[MAXB];
    __shared__ int gbase[MAXB];
    __shared__ int wsums[4];
    __shared__ uint32 staged[PCHUNK];
    __shared__ unsigned char bslot[PCHUNK];
    int t = threadIdx.x;
    int lane = t & 63, w = t >> 6;
    int eb = blockIdx.x * PCHUNK;
    int sreg[PEPT], dreg[PEPT];
    #pragma unroll
    for (int k = 0; k < PEPT; ++k) {
        int e = eb + k * 256 + t;
        if (e < TOT) {
            if (e < E) { sreg[k] = ei[e]; dreg[k] = ei[E + e]; }
            else       { sreg[k] = dreg[k] = e - E; }
        } else dreg[k] = -1;
    }
    lcnt[t] = 0;
    __syncthreads();
    #pragma unroll
    for (int k = 0; k < PEPT; ++k)
        if (dreg[k] >= 0) atomicAdd(&lcnt[dreg[k] >> BSHIFT], 1);
    __syncthreads();
    int v = lcnt[t];
    int incl = v;
    #pragma unroll
    for (int off = 1; off < 64; off <<= 1) {
        int u = __shfl_up(incl, off);
        if (lane >= off) incl += u;
    }
    if (lane == 63) wsums[w] = incl;
    __syncthreads();
    int wadd = 0;
    #pragma unroll
    for (int k = 0; k < 4; ++k) wadd += (k < w) ? wsums[k] : 0;
    int ex = incl + wadd - v;
    lstart[t] = ex;
    lcur[t] = ex;
    if (v > 0) gbase[t] = t * BSTRIDE + atomicAdd(&gcur0[t], v);
    __syncthreads();
    #pragma unroll
    for (int k = 0; k < PEPT; ++k) {
        int d = dreg[k];
        if (d >= 0) {
            int b = d >> BSHIFT;
            int p = atomicAdd(&lcur[b], 1);
            staged[p] = ((uint32)(d & (BSIZE - 1)) << 17) | (uint32)sreg[k];
            bslot[p] = (unsigned char)b;
        }
    }
    __syncthreads();
    int nvalid = TOT - eb; if (nvalid > PCHUNK) nvalid = PCHUNK;
    for (int i = t; i < nvalid; i += 256) {
        int b = bslot[i];
        tmp[gbase[b] + (i - lstart[b])] = staged[i];
    }
}

// ------------- per-bucket: per-node scan -> rowptr/rowend + col -----------
__global__ __launch_bounds__(1024) void bucket_build(const uint32* __restrict__ tmp,
                                                     const int* __restrict__ gcur0,
                                                     int* __restrict__ rowptr,
                                                     int* __restrict__ rowend,
                                                     int* __restrict__ col,
                                                     int N, int NB) {
    __shared__ int cnt[BSIZE];
    __shared__ int bsums[4];
    int b = blockIdx.x, t = threadIdx.x;
    int lo = b << BSHIFT;
    int nn = N - lo; if (nn > BSIZE) nn = BSIZE;
    if (t < BSIZE) cnt[t] = 0;
    __syncthreads();
    int ebeg = b * BSTRIDE;
    int eend = ebeg + gcur0[b];
    for (int i = ebeg + t; i < eend; i += 1024)
        atomicAdd(&cnt[tmp[i] >> 17], 1);
    __syncthreads();
    int c0 = 0, c1 = 0, s2 = 0;
    if (t < 256) {
        c0 = cnt[2 * t]; c1 = cnt[2 * t + 1];
        s2 = c0 + c1;
    }
    // wave shfl scan over the 256 participating threads (4 waves)
    int lane = t & 63, w = t >> 6;
    int incl = s2;
    #pragma unroll
    for (int off = 1; off < 64; off <<= 1) {
        int u = __shfl_up(incl, off);
        if (lane >= off) incl += u;
    }
    if (t < 256 && lane == 63) bsums[w] = incl;
    __syncthreads();
    if (t < 256) {
        int wadd = 0;
        #pragma unroll
        for (int k = 0; k < 4; ++k) wadd += (k < w) ? bsums[k] : 0;
        int ex = incl + wadd - s2;
        int st0 = ebeg + ex, st1 = st0 + c0;
        if (2 * t < nn)     { rowptr[lo + 2 * t] = st0;     rowend[lo + 2 * t] = st0 + c0; }
        if (2 * t + 1 < nn) { rowptr[lo + 2 * t + 1] = st1; rowend[lo + 2 * t + 1] = st1 + c1; }
        cnt[2 * t] = st0; cnt[2 * t + 1] = st1;
    }
    __syncthreads();
    for (int i = ebeg + t; i < eend; i += 1024) {
        uint32 u = tmp[i];
        int p = atomicAdd(&cnt[u >> 17], 1);
        col[p] = (int)(u & 0x1FFFFu);
    }
}

// ---- shared MFMA core: A(bf16) x (B_hi + B_lo), 32 rows/wave -------------
// FP8: pack hb rows as OCP e4m3 (128 B/row) for the gather.
template<bool FP8>
__device__ __forceinline__ void gemm_core(const bf16x8 ah[2][4],
                                          const __bf16* Wl,
                                          const float* a_src, const float* a_dst,
                                          uint32* hb, float* as_, float* ad_,
                                          int rbase, int n, int col16, int quad) {
    f32x4 acc[2][8];
    #pragma unroll
    for (int mt = 0; mt < 2; ++mt)
        #pragma unroll
        for (int t = 0; t < 8; ++t) acc[mt][t] = (f32x4)(0.0f);

    #pragma unroll
    for (int c = 0; c < 4; ++c) {
        #pragma unroll
        for (int t = 0; t < 8; ++t) {
            int off = (((c * 4 + quad) * 128) + t * 16 + col16) * 8;
            bf16x8 bh = *(const bf16x8*)&Wl[off];
            bf16x8 bl = *(const bf16x8*)&Wl[16384 + off];
            #pragma unroll
            for (int mt = 0; mt < 2; ++mt) {
                acc[mt][t] = __builtin_amdgcn_mfma_f32_16x16x32_bf16(ah[mt][c], bh, acc[mt][t], 0, 0, 0);
                acc[mt][t] = __builtin_amdgcn_mfma_f32_16x16x32_bf16(ah[mt][c], bl, acc[mt][t], 0, 0, 0);
            }
        }
    }
    float asv[8], adv[8];
    #pragma unroll
    for (int t = 0; t < 8; ++t) { asv[t] = a_src[t * 16 + col16]; adv[t] = a_dst[t * 16 + col16]; }
    #pragma unroll
    for (int mt = 0; mt < 2; ++mt) {
        #pragma unroll
        for (int reg = 0; reg < 4; ++reg) {
            float s = 0.0f, d = 0.0f;
            #pragma unroll
            for (int t = 0; t < 8; ++t) {
                float v = acc[mt][t][reg];
                s += v * asv[t]; d += v * adv[t];
            }
            #pragma unroll
            for (int off = 1; off < 16; off <<= 1) {
                s += __shfl_xor(s, off);
                d += __shfl_xor(d, off);
            }
            int r = rbase + mt * 16 + quad * 4 + reg;
            if (col16 == 0 && r < n) { as_[r] = s; ad_[r] = d; }
        }
    }
    #pragma unroll
    for (int mt = 0; mt < 2; ++mt)
    #pragma unroll
    for (int t = 0; t < 8; ++t)
    #pragma unroll
    for (int reg = 0; reg < 4; ++reg) {
        float v = acc[mt][t][reg];
        int r = rbase + mt * 16 + quad * 4 + reg;
        if (FP8) {
            float p1 = __shfl_xor(v, 1);
            uint32 pk = (uint32)__builtin_amdgcn_cvt_pk_fp8_f32(v, p1, 0, false);
            uint32 pk2 = __shfl_xor(pk, 2);
            if (!(col16 & 3) && r < n)
                hb[(size_t)r * 32 + t * 4 + (col16 >> 2)] = (pk & 0xffffu) | (pk2 << 16);
        } else {
            float p = __shfl_xor(v, 1);
            if (!(col16 & 1) && r < n) {
                uint32 pkb = (uint32)f2bf(v) | ((uint32)f2bf(p) << 16);
                hb[(size_t)r * 64 + t * 8 + (col16 >> 1)] = pkb;
            }
        }
    }
}

// 512-thread blocks: 256 rows/block, same 64KB LDS -> 16 waves/CU
// both gemms emit FP8 hb rows (128 B/row gather buffer)
__global__ __launch_bounds__(512) void gemm_mfma_f32(const float* __restrict__ X,
                                                     const unsigned short* __restrict__ Wbh,
                                                     const float* __restrict__ a_src,
                                                     const float* __restrict__ a_dst,
                                                     uint32* __restrict__ hb,
                                                     float* __restrict__ as_,
                                                     float* __restrict__ ad_, int n) {
    __shared__ __bf16 Wl[32768];   // 64 KB hi+lo
    const int tid = threadIdx.x;
    {
        const uint4* sw = (const uint4*)Wbh;
        uint4* dw = (uint4*)Wl;
        for (int i = tid; i < 4096; i += 512) dw[i] = sw[i];
    }
    const int lane = tid & 63, wid = tid >> 6;
    const int col16 = lane & 15, quad = lane >> 4;
    const int rbase = blockIdx.x * 256 + wid * 32;
    bf16x8 ah[2][4];
    #pragma unroll
    for (int mt = 0; mt < 2; ++mt) {
        int r = rbase + mt * 16 + col16;
        bool ok = (r < n);
        const float* xp = X + (size_t)r * 128;
        #pragma unroll
        for (int c = 0; c < 4; ++c) {
            int k0 = c * 32 + quad * 8;
            float4 x0 = ok ? *(const float4*)(xp + k0)     : make_float4(0.f,0.f,0.f,0.f);
            float4 x1 = ok ? *(const float4*)(xp + k0 + 4) : make_float4(0.f,0.f,0.f,0.f);
            float xs[8] = {x0.x,x0.y,x0.z,x0.w,x1.x,x1.y,x1.z,x1.w};
            #pragma unroll
            for (int j = 0; j < 8; ++j) ah[mt][c][j] = (__bf16)xs[j];
        }
    }
    __syncthreads();
    gemm_core<true>(ah, Wl, a_src, a_dst, hb, as_, ad_, rbase, n, col16, quad);
}

__global__ __launch_bounds__(512) void gemm_mfma_bf16(const __bf16* __restrict__ X,
                                                      const unsigned short* __restrict__ Wbh,
                                                      const float* __restrict__ a_src,
                                                      const float* __restrict__ a_dst,
                                                      uint32* __restrict__ hb,
                                                      float* __restrict__ as_,
                                                      float* __restrict__ ad_, int n) {
    __shared__ __bf16 Wl[32768];
    const int tid = threadIdx.x;
    {
        const uint4* sw = (const uint4*)Wbh;
        uint4* dw = (uint4*)Wl;
        for (int i = tid; i < 4096; i += 512) dw[i] = sw[i];
    }
    const int lane = tid & 63, wid = tid >> 6;
    const int col16 = lane & 15, quad = lane >> 4;
    const int rbase = blockIdx.x * 256 + wid * 32;
    bf16x8 ah[2][4];
    const bf16x8 zz = (bf16x8)((__bf16)0.0f);
    #pragma unroll
    for (int mt = 0; mt < 2; ++mt) {
        int r = rbase + mt * 16 + col16;
        bool ok = (r < n);
        const __bf16* xp = X + (size_t)r * 128;
        #pragma unroll
        for (int c = 0; c < 4; ++c)
            ah[mt][c] = ok ? *(const bf16x8*)(xp + c * 32 + quad * 8) : zz;
    }
    __syncthreads();
    gemm_core<true>(ah, Wl, a_src, a_dst, hb, as_, ad_, rbase, n, col16, quad);
}

// --------- fused GAT fp8 (proven 52.4us): no LDS, no barriers, loads-first
// 4 nodes/wave x 16 lanes, 128B rows (uint2/lane), HW cvt decode.
// R9 lesson: do NOT widen to paired-row uint4 loads — halving the
// outstanding-request count (the real MLP resource) cost +35%.
#define GIDX8(SARR, T0) { _Pragma("unroll") \
    for (int k_ = 0; k_ < 8; ++k_) { int t_ = (T0) + k_; \
        int sv_ = (t_ < 16) ? s0 : s1; \
        int si_ = __shfl(sv_, base + (t_ & 15)); \
        SARR[k_] = (t_ < cnt) ? si_ : 0; } }

#define GW8(WARR, T0) { _Pragma("unroll") \
    for (int k_ = 0; k_ < 8; ++k_) { int t_ = (T0) + k_; \
        float wv_ = (t_ < 16) ? w0 : w1; \
        float wf_ = __shfl(wv_, base + (t_ & 15)); \
        WARR[k_] = (t_ < cnt) ? wf_ : 0.0f; } }

#define GLOAD8_F8(GARR, SARR) { _Pragma("unroll") \
    for (int k_ = 0; k_ < 8; ++k_) GARR[k_] = hb2[(uint32)SARR[k_] * 16u + l]; }

#define GCONSUME_F8(GARR, WARR) { _Pragma("unroll") \
    for (int k_ = 0; k_ < 8; ++k_) { \
        f32x2 wv_ = (f32x2)WARR[k_]; \
        ac[0] = __builtin_elementwise_fma(wv_, f8x2lo(GARR[k_].x), ac[0]); \
        ac[1] = __builtin_elementwise_fma(wv_, f8x2hi(GARR[k_].x), ac[1]); \
        ac[2] = __builtin_elementwise_fma(wv_, f8x2lo(GARR[k_].y), ac[2]); \
        ac[3] = __builtin_elementwise_fma(wv_, f8x2hi(GARR[k_].y), ac[3]); } }

__global__ __launch_bounds__(256) void gat_csr5_f8(const int* __restrict__ rowptr,
                                                   const int* __restrict__ rowend,
                                                   const int* __restrict__ col,
                                                   const uint2* __restrict__ hb2,
                                                   const float* __restrict__ as_,
                                                   const float* __restrict__ ad_,
                                                   const float* __restrict__ bias,
                                                   uint4* __restrict__ outb, int n) {
    const int wid = threadIdx.x >> 6;
    const int lane = threadIdx.x & 63;
    const int q = lane >> 4, l = lane & 15;
    const int base = lane & 48;
    const int node = blockIdx.x * 16 + wid * 4 + q;
    const bool valid = node < n;
    int beg = 0, end = 0;
    if (valid) { beg = rowptr[node]; end = rowend[node]; }
    float add = valid ? ad_[node] : 0.0f;
    int deg = end - beg;
    int m1 = max(deg, __shfl_xor(deg, 16));
    int mdeg = max(m1, __shfl_xor(m1, 32));
    float s = 0.0f;
    f32x2 ac[4];
    #pragma unroll
    for (int p = 0; p < 4; ++p) ac[p] = (f32x2)(0.0f);

    for (int cb = 0; cb < mdeg; cb += 32) {
        int j0 = beg + cb + l, j1 = j0 + 16;
        bool e0 = (j0 < end), e1 = (j1 < end);
        int s0 = e0 ? col[j0] : 0;
        int s1 = e1 ? col[j1] : 0;
        int cnt = end - beg - cb;
        cnt = (cnt < 0) ? 0 : (cnt > 32 ? 32 : cnt);
        int rem = mdeg - cb; if (rem > 32) rem = 32;
        const int NB8 = (rem + 7) >> 3;

        int si[8]; uint2 gA[8], gB[8]; float wA[8], wB[8];

        // batch 0 loads go out first -- alpha phase hides under them
        GIDX8(si, 0); GLOAD8_F8(gA, si);

        float v0 = as_[s0] + add;
        float v1 = as_[s1] + add;
        v0 = (v0 > 0.0f) ? v0 : NEG_SLOPE * v0;
        v1 = (v1 > 0.0f) ? v1 : NEG_SLOPE * v1;
        float w0 = e0 ? __expf(v0) : 0.0f;
        float w1 = e1 ? __expf(v1) : 0.0f;
        float ws = w0 + w1;
        #pragma unroll
        for (int off = 8; off > 0; off >>= 1) ws += __shfl_xor(ws, off);
        s += ws;
        GW8(wA, 0);

        int b = 0;
        while (true) {
            bool moreB = (b + 1 < NB8);
            if (moreB) { GIDX8(si, (b + 1) * 8); GLOAD8_F8(gB, si); GW8(wB, (b + 1) * 8); }
            GCONSUME_F8(gA, wA);
            if (!moreB) break;
            bool moreA = (b + 2 < NB8);
            if (moreA) { GIDX8(si, (b + 2) * 8); GLOAD8_F8(gA, si); GW8(wA, (b + 2) * 8); }
            GCONSUME_F8(gB, wB);
            if (!moreA) break;
            b += 2;
        }
    }
    if (valid) {
        float inv = 1.0f / s;
        float4 b0 = *(const float4*)&bias[l * 8];
        float4 b1 = *(const float4*)&bias[l * 8 + 4];
        float r0 = selu_f(ac[0].x * inv + b0.x);
        float r1 = selu_f(ac[0].y * inv + b0.y);
        float r2 = selu_f(ac[1].x * inv + b0.z);
        float r3 = selu_f(ac[1].y * inv + b0.w);
        float r4 = selu_f(ac[2].x * inv + b1.x);
        float r5 = selu_f(ac[2].y * inv + b1.y);
        float r6 = selu_f(ac[3].x * inv + b1.z);
        float r7 = selu_f(ac[3].y * inv + b1.w);
        uint4 o;
        o.x = (uint32)f2bf(r0) | ((uint32)f2bf(r1) << 16);
        o.y = (uint32)f2bf(r2) | ((uint32)f2bf(r3) << 16);
        o.z = (uint32)f2bf(r4) | ((uint32)f2bf(r5) << 16);
        o.w = (uint32)f2bf(r6) | ((uint32)f2bf(r7) << 16);
        outb[(uint32)node * 16u + l] = o;
    }
}

// ------- streaming mean-pool: coalesced read of h2b, reg-accum by graph ---
__global__ __launch_bounds__(256) void pool_stream(const uint32* __restrict__ act,
                                                   const int* __restrict__ batch,
                                                   float* __restrict__ gsum, int N) {
    __shared__ float pacc[PSPAN][128];
    const int t = threadIdx.x, wid = t >> 6, u = t & 63;
    const int n0 = blockIdx.x * PNODES;
    int n1 = n0 + PNODES; if (n1 > N) n1 = N;
    for (int i = t; i < PSPAN * 128; i += 256) pacc[i >> 7][i & 127] = 0.f;
    __syncthreads();
    const int gfirst = batch[n0];
    float a0 = 0.f, a1 = 0.f;
    int gcur = gfirst;
    for (int nd = n0 + wid; nd < n1; nd += 4) {
        int g = batch[nd];
        if (g != gcur) {
            int slot = gcur - gfirst;
            if (slot < PSPAN) {
                atomicAdd(&pacc[slot][2 * u], a0);
                atomicAdd(&pacc[slot][2 * u + 1], a1);
            } else {
                atomicAdd(&gsum[(size_t)gcur * 128 + 2 * u], a0);
                atomicAdd(&gsum[(size_t)gcur * 128 + 2 * u + 1], a1);
            }
            a0 = a1 = 0.f; gcur = g;
        }
        uint32 gv = act[(size_t)nd * 64 + u];
        a0 += bf_lo(gv); a1 += bf_hi(gv);
    }
    {
        int slot = gcur - gfirst;
        if (slot < PSPAN) {
            atomicAdd(&pacc[slot][2 * u], a0);
            atomicAdd(&pacc[slot][2 * u + 1], a1);
        } else {
            atomicAdd(&gsum[(size_t)gcur * 128 + 2 * u], a0);
            atomicAdd(&gsum[(size_t)gcur * 128 + 2 * u + 1], a1);
        }
    }
    __syncthreads();
    int lastg = batch[n1 - 1];
    int nslots = lastg - gfirst + 1; if (nslots > PSPAN) nslots = PSPAN;
    for (int i = t; i < nslots * 128; i += 256) {
        float v = pacc[i >> 7][i & 127];
        if (v != 0.f)
            atomicAdd(&gsum[(size_t)(gfirst + (i >> 7)) * 128 + (i & 127)], v);
    }
}

// ------------- head: mean from gsum (fp32) + MLP + log-softmax ------------
__global__ __launch_bounds__(128) void pool_head2(const float* __restrict__ gsum,
                                                  const int* __restrict__ gstart,
                                                  const float* __restrict__ Wfc1,
                                                  const float* __restrict__ bfc1,
                                                  const float* __restrict__ Wfc2,
                                                  const float* __restrict__ bfc2,
                                                  float* __restrict__ out) {
    __shared__ float p[128];
    __shared__ float q[64];
    __shared__ float l[10];
    __shared__ float red[2];
    int g = blockIdx.x, t = threadIdx.x;
    int lo = gstart[g], hi = gstart[g + 1];
    float c = fmaxf((float)(hi - lo), 1.0f);
    p[t] = selu_f(gsum[(size_t)g * 128 + t] / c);
    __syncthreads();
    if (t < 64) {
        float a = bfc1[t];
        #pragma unroll 8
        for (int k = 0; k < 128; ++k) a += p[k] * Wfc1[k * 64 + t];
        q[t] = selu_f(a);
    }
    __syncthreads();
    if (t < 10) {
        float a = bfc2[t];
        #pragma unroll
        for (int k = 0; k < 64; ++k) a += q[k] * Wfc2[k * 10 + t];
        l[t] = a;
    }
    __syncthreads();
    if (t == 0) {
        float mx = l[0];
        for (int c2 = 1; c2 < 10; ++c2) mx = fmaxf(mx, l[c2]);
        float sum = 0.0f;
        for (int c2 = 0; c2 < 10; ++c2) sum += __expf(l[c2] - mx);
        red[0] = mx; red[1] = logf(sum);
    }
    __syncthreads();
    if (t < 10) out[g * 10 + t] = l[t] - red[0] - red[1];
}

extern "C" void kernel_launch(void* const* d_in, const int* in_sizes, int n_in,
                              void* d_out, int out_size, void* d_ws, size_t ws_size,
                              hipStream_t stream) {
    const float* x      = (const float*)d_in[0];
    const int*   ei     = (const int*)d_in[1];
    const int*   batch  = (const int*)d_in[2];
    const float* W1     = (const float*)d_in[3];
    const float* asrc1  = (const float*)d_in[4];
    const float* adst1  = (const float*)d_in[5];
    const float* b1     = (const float*)d_in[6];
    const float* W2     = (const float*)d_in[7];
    const float* asrc2  = (const float*)d_in[8];
    const float* adst2  = (const float*)d_in[9];
    const float* b2     = (const float*)d_in[10];
    const float* Wfc1   = (const float*)d_in[11];
    const float* bfc1   = (const float*)d_in[12];
    const float* Wfc2   = (const float*)d_in[13];
    const float* bfc2   = (const float*)d_in[14];
    float* out = (float*)d_out;

    const int N = in_sizes[0] / 128;
    const int E = in_sizes[1] / 2;
    const int G = out_size / 10;
    const int TOT = E + N;
    const int NB = ((N - 1) >> BSHIFT) + 1;
    const int GB = (N + 255) / 256;
    const int PH = (TOT + PCHUNK - 1) / PCHUNK;
    const int GemmG = (N + 255) / 256;

    // workspace layout
    uint32* hb    = (uint32*)d_ws;                   // N*64  (h rows: fp8, 128B used)
    uint32* h2b   = hb + (size_t)N * 64;             // N*64  (bf16 layer outputs)
    uint32* tmp   = h2b + (size_t)N * 64;            // NB*BSTRIDE (strided buckets)
    int*    col   = (int*)(tmp + (size_t)NB * BSTRIDE); // NB*BSTRIDE (strided)
    float* as_    = (float*)(col + (size_t)NB * BSTRIDE); // N
    float* ad_    = as_ + N;                         // N
    int*   gstart = (int*)(ad_ + N);                 // G+1
    int*   rowptr = gstart + (G + 2);                // N
    int*   rowend = rowptr + (N + 2);                // N
    int*   gcur0  = rowend + (N + 2);                // MAXB (zeroed in prep9)
    unsigned short* Wb = (unsigned short*)(((uintptr_t)(gcur0 + MAXB) + 255) & ~(uintptr_t)255);
    // Wb: 2 layers x (16384 hi + 16384 lo) ushorts = 128 KB
    float* gsum = (float*)(Wb + 2 * 32768);          // G*128 fp32 pooled sums

    const int gatGrid = (N + 15) / 16;

    // ---------------- prep (repack + gbounds + zeroing) + CSR build -------
    prep9<<<2 + GB, 256, 0, stream>>>(W1, W2, Wb, batch, gstart, gcur0, gsum, N, G);
    partition_edges<<<PH, 256, 0, stream>>>(ei, gcur0, tmp, E, TOT);
    bucket_build<<<NB, 1024, 0, stream>>>(tmp, gcur0, rowptr, rowend, col, N, NB);

    // ---------------- layer 1 (fp8 gather; attention logits stay fp32) ----
    gemm_mfma_f32<<<GemmG, 512, 0, stream>>>(x, Wb, asrc1, adst1, hb, as_, ad_, N);
    gat_csr5_f8<<<gatGrid, 256, 0, stream>>>(rowptr, rowend, col, (const uint2*)hb,
                                             as_, ad_, b1, (uint4*)h2b, N);

    // ---------------- layer 2 (fp8 gather) ----------------
    gemm_mfma_bf16<<<GemmG, 512, 0, stream>>>((const __bf16*)h2b, Wb + 32768, asrc2, adst2, hb, as_, ad_, N);
    gat_csr5_f8<<<gatGrid, 256, 0, stream>>>(rowptr, rowend, col, (const uint2*)hb,
                                             as_, ad_, b2, (uint4*)h2b, N);

    // ---------------- pool (streaming) + head ----------------
    pool_stream<<<(N + PNODES - 1) / PNODES, 256, 0, stream>>>(h2b, batch, gsum, N);
    pool_head2<<<G, 128, 0, stream>>>(gsum, gstart, Wfc1, bfc1, Wfc2, bfc2, out);
}